// Round 1
// baseline (235.444 us; speedup 1.0000x reference)
//
#include <hip/hip_runtime.h>

typedef __attribute__((ext_vector_type(8))) short short8;
typedef __attribute__((ext_vector_type(4))) float f32x4;

#define NSONG 100000
#define DIM   128
#define BATCH 32
#define SEQ   20
#define NCHUNK 8
#define CHUNK (NSONG / NCHUNK) /* 12500 */

__device__ __forceinline__ unsigned short f2bf(float f) {
    unsigned int u = __float_as_uint(f);
    unsigned int r = u + 0x7FFFu + ((u >> 16) & 1u);
    return (unsigned short)(r >> 16);
}

// online softmax update: (m,z) <- include value v
__device__ __forceinline__ void onl(float& m, float& z, float v) {
    if (v > m) { z = z * __expf(m - v) + 1.0f; m = v; }
    else       { z += __expf(v - m); }
}
// combine two online pairs
__device__ __forceinline__ void onl_comb(float& m, float& z, float om, float oz) {
    float M = fmaxf(m, om);
    z = z * __expf(m - M) + oz * __expf(om - M);
    m = M;
}

// K1: normalize pred rows -> packed bf16 [32 b][32 rows (20 real + 12 zero)][128]
__global__ __launch_bounds__(64) void k_prednorm(const float* __restrict__ pred,
                                                 unsigned int* __restrict__ predp) {
    int r = blockIdx.x;           // 0..1023 = b*32 + s
    int b = r >> 5, s = r & 31;
    int lane = threadIdx.x;       // 0..63, each handles 2 elems
    unsigned int* orow = predp + (size_t)r * (DIM / 2);
    if (s < SEQ) {
        const float2* src = (const float2*)(pred + (size_t)(b * SEQ + s) * DIM);
        float2 v = src[lane];
        float ss = v.x * v.x + v.y * v.y;
        #pragma unroll
        for (int d = 1; d < 64; d <<= 1) ss += __shfl_xor(ss, d);
        float sc = 1.0f / fmaxf(sqrtf(ss), 1e-8f);
        unsigned int lo = f2bf(v.x * sc);
        unsigned int hi = f2bf(v.y * sc);
        orow[lane] = lo | (hi << 16);
    } else {
        orow[lane] = 0u;
    }
}

// K2: sim[b][n] = max_s pred_n[b,s] . song_n[n]  via mfma 16x16x32 bf16
// one wave = 16 songs; songs normalized on the fly, B-frags held in regs.
__global__ __launch_bounds__(256) void k_simmax(const float* __restrict__ song,
                                                const unsigned short* __restrict__ predp,
                                                float* __restrict__ sim) {
    int lane = threadIdx.x & 63;
    int wid  = threadIdx.x >> 6;
    int song0 = (blockIdx.x * 4 + wid) * 16;
    if (song0 >= NSONG) return;           // no __syncthreads in this kernel
    int l16 = lane & 15;
    int grp = lane >> 4;

    const float* srow = song + (size_t)(song0 + l16) * DIM;

    // load this song's 32 k-values (per lane), accumulate sumsq
    float v[4][8];
    float ss = 0.0f;
    #pragma unroll
    for (int kt = 0; kt < 4; ++kt) {
        int kb = kt * 32 + grp * 8;
        float4 u0 = *(const float4*)(srow + kb);
        float4 u1 = *(const float4*)(srow + kb + 4);
        v[kt][0] = u0.x; v[kt][1] = u0.y; v[kt][2] = u0.z; v[kt][3] = u0.w;
        v[kt][4] = u1.x; v[kt][5] = u1.y; v[kt][6] = u1.z; v[kt][7] = u1.w;
        #pragma unroll
        for (int j = 0; j < 8; ++j) ss += v[kt][j] * v[kt][j];
    }
    // full-row sumsq: combine the 4 lane-groups holding the same song
    ss += __shfl_xor(ss, 16);
    ss += __shfl_xor(ss, 32);
    float sc = 1.0f / fmaxf(sqrtf(ss), 1e-8f);

    short8 bfrag[4];
    #pragma unroll
    for (int kt = 0; kt < 4; ++kt) {
        #pragma unroll
        for (int j = 0; j < 8; ++j) bfrag[kt][j] = (short)f2bf(v[kt][j] * sc);
    }

    #pragma unroll 1
    for (int b = 0; b < BATCH; ++b) {
        const unsigned short* abase = predp + (size_t)b * 32 * DIM;
        f32x4 acc0 = {0.f, 0.f, 0.f, 0.f};
        f32x4 acc1 = {0.f, 0.f, 0.f, 0.f};
        #pragma unroll
        for (int kt = 0; kt < 4; ++kt) {
            int kb = kt * 32 + grp * 8;
            short8 a0 = *(const short8*)(abase + (size_t)l16 * DIM + kb);
            short8 a1 = *(const short8*)(abase + (size_t)(16 + l16) * DIM + kb);
            acc0 = __builtin_amdgcn_mfma_f32_16x16x32_bf16(a0, bfrag[kt], acc0, 0, 0, 0);
            acc1 = __builtin_amdgcn_mfma_f32_16x16x32_bf16(a1, bfrag[kt], acc1, 0, 0, 0);
        }
        // C layout: col = lane&15 (song), row = grp*4+reg (pred row in tile)
        // acc0 rows 0..15 all valid (<20); acc1 rows 16..31 valid only 16..19 (grp==0)
        float m = fmaxf(fmaxf(acc0[0], acc0[1]), fmaxf(acc0[2], acc0[3]));
        if (grp == 0) {
            float m1 = fmaxf(fmaxf(acc1[0], acc1[1]), fmaxf(acc1[2], acc1[3]));
            m = fmaxf(m, m1);
        }
        m = fmaxf(m, __shfl_xor(m, 16));
        m = fmaxf(m, __shfl_xor(m, 32));
        if (lane < 16) sim[(size_t)b * NSONG + song0 + lane] = m;
    }
}

// K3a: per (b, chunk) online-softmax stats for sim*x_inv and for y
__global__ __launch_bounds__(256) void k_stats1(const float* __restrict__ sim,
                                                const float* __restrict__ x_inv,
                                                const float* __restrict__ y,
                                                float* __restrict__ pm, float* __restrict__ pz,
                                                float* __restrict__ pym, float* __restrict__ pyz) {
    int b = blockIdx.x >> 3, c = blockIdx.x & 7;
    int tid = threadIdx.x;
    size_t base = (size_t)b * NSONG + (size_t)c * CHUNK;
    const float4* s4 = (const float4*)(sim + base);
    const float4* x4 = (const float4*)(x_inv + base);
    const float4* y4 = (const float4*)(y + base);
    float m = -3.0e38f, z = 0.f, ym = -3.0e38f, yz = 0.f;
    for (int i = tid; i < CHUNK / 4; i += 256) {
        float4 sv = s4[i], xv = x4[i], yv = y4[i];
        onl(m, z, sv.x * xv.x); onl(m, z, sv.y * xv.y);
        onl(m, z, sv.z * xv.z); onl(m, z, sv.w * xv.w);
        onl(ym, yz, yv.x); onl(ym, yz, yv.y);
        onl(ym, yz, yv.z); onl(ym, yz, yv.w);
    }
    #pragma unroll
    for (int d = 1; d < 64; d <<= 1) {
        float om = __shfl_xor(m, d), oz = __shfl_xor(z, d);
        onl_comb(m, z, om, oz);
        float oym = __shfl_xor(ym, d), oyz = __shfl_xor(yz, d);
        onl_comb(ym, yz, oym, oyz);
    }
    __shared__ float sm[4], sz[4], sym[4], syz[4];
    int w = tid >> 6;
    if ((tid & 63) == 0) { sm[w] = m; sz[w] = z; sym[w] = ym; syz[w] = yz; }
    __syncthreads();
    if (tid == 0) {
        float M = sm[0], Z = sz[0], YM = sym[0], YZ = syz[0];
        for (int j = 1; j < 4; ++j) {
            onl_comb(M, Z, sm[j], sz[j]);
            onl_comb(YM, YZ, sym[j], syz[j]);
        }
        pm[blockIdx.x] = M; pz[blockIdx.x] = Z;
        pym[blockIdx.x] = YM; pyz[blockIdx.x] = YZ;
    }
}

// K3c: per (b, chunk) partial E = sum exp(p), T = sum t*p
__global__ __launch_bounds__(256) void k_stats2(const float* __restrict__ sim,
                                                const float* __restrict__ x_inv,
                                                const float* __restrict__ y,
                                                const float* __restrict__ pm, const float* __restrict__ pz,
                                                const float* __restrict__ pym, const float* __restrict__ pyz,
                                                float* __restrict__ pe, float* __restrict__ pt) {
    int b = blockIdx.x >> 3, c = blockIdx.x & 7;
    int tid = threadIdx.x;
    // combine the 8 chunk stats (redundant per thread; 8 iterations, cheap)
    float M = pm[b * 8], Z = pz[b * 8], YM = pym[b * 8], YZ = pyz[b * 8];
    #pragma unroll
    for (int j = 1; j < 8; ++j) {
        onl_comb(M, Z, pm[b * 8 + j], pz[b * 8 + j]);
        onl_comb(YM, YZ, pym[b * 8 + j], pyz[b * 8 + j]);
    }
    float invZ = 1.0f / Z, invY = 1.0f / YZ;
    size_t base = (size_t)b * NSONG + (size_t)c * CHUNK;
    const float4* s4 = (const float4*)(sim + base);
    const float4* x4 = (const float4*)(x_inv + base);
    const float4* y4 = (const float4*)(y + base);
    float e = 0.f, t = 0.f;
    for (int i = tid; i < CHUNK / 4; i += 256) {
        float4 sv = s4[i], xv = x4[i], yv = y4[i];
        float p0 = __expf(sv.x * xv.x - M) * invZ;
        float p1 = __expf(sv.y * xv.y - M) * invZ;
        float p2 = __expf(sv.z * xv.z - M) * invZ;
        float p3 = __expf(sv.w * xv.w - M) * invZ;
        e += __expf(p0) + __expf(p1) + __expf(p2) + __expf(p3);
        t += __expf(yv.x - YM) * invY * p0;
        t += __expf(yv.y - YM) * invY * p1;
        t += __expf(yv.z - YM) * invY * p2;
        t += __expf(yv.w - YM) * invY * p3;
    }
    #pragma unroll
    for (int d = 1; d < 64; d <<= 1) {
        e += __shfl_xor(e, d);
        t += __shfl_xor(t, d);
    }
    __shared__ float se[4], st[4];
    int w = tid >> 6;
    if ((tid & 63) == 0) { se[w] = e; st[w] = t; }
    __syncthreads();
    if (tid == 0) {
        float E = se[0] + se[1] + se[2] + se[3];
        float T = st[0] + st[1] + st[2] + st[3];
        pe[blockIdx.x] = E; pt[blockIdx.x] = T;
    }
}

// K4: loss_b = log(E_b) - T_b ; out = mean_b
__global__ __launch_bounds__(64) void k_final(const float* __restrict__ pe,
                                              const float* __restrict__ pt,
                                              float* __restrict__ out) {
    int lane = threadIdx.x;
    float loss = 0.f;
    if (lane < BATCH) {
        float E = 0.f, T = 0.f;
        #pragma unroll
        for (int j = 0; j < 8; ++j) { E += pe[lane * 8 + j]; T += pt[lane * 8 + j]; }
        loss = logf(E) - T;
    }
    #pragma unroll
    for (int d = 1; d < 64; d <<= 1) loss += __shfl_xor(loss, d);
    if (lane == 0) out[0] = loss * (1.0f / BATCH);
}

extern "C" void kernel_launch(void* const* d_in, const int* in_sizes, int n_in,
                              void* d_out, int out_size, void* d_ws, size_t ws_size,
                              hipStream_t stream) {
    const float* pred  = (const float*)d_in[0];
    const float* song  = (const float*)d_in[1];
    const float* x_inv = (const float*)d_in[2];
    const float* y     = (const float*)d_in[3];
    float* out = (float*)d_out;

    char* ws = (char*)d_ws;
    unsigned short* predp = (unsigned short*)ws;                 // 32*32*128*2 = 256 KiB
    float* sim = (float*)(ws + 262144);                          // 32*100000*4 = 12.8 MB
    float* st  = (float*)(ws + 262144 + 12800000);               // stats
    float* pm  = st;        float* pz  = st + 256;
    float* pym = st + 512;  float* pyz = st + 768;
    float* pe  = st + 1024; float* pt  = st + 1280;

    k_prednorm<<<BATCH * 32, 64, 0, stream>>>(pred, (unsigned int*)predp);
    k_simmax<<<(NSONG / 16 + 3) / 4, 256, 0, stream>>>(song, predp, sim);
    k_stats1<<<BATCH * NCHUNK, 256, 0, stream>>>(sim, x_inv, y, pm, pz, pym, pyz);
    k_stats2<<<BATCH * NCHUNK, 256, 0, stream>>>(sim, x_inv, y, pm, pz, pym, pyz, pe, pt);
    k_final<<<1, 64, 0, stream>>>(pe, pt, out);
}

// Round 2
// 78.124 us; speedup vs baseline: 3.0137x; 3.0137x over previous
//
#include <hip/hip_runtime.h>

typedef __attribute__((ext_vector_type(8))) short short8;
typedef __attribute__((ext_vector_type(4))) float f32x4;

#define NS    100000
#define DIM   128
#define BATCH 32
#define SEQ   20
#define NBLK  782              /* ceil(100000 / 128) */
#define NWAVES (NBLK * 4)      /* 3128 */
#define PW    3136

typedef const __attribute__((address_space(1))) unsigned int g_u32;
typedef __attribute__((address_space(3))) unsigned int l_u32;

__device__ __forceinline__ unsigned short f2bf(float f) {
    unsigned int u = __float_as_uint(f);
    unsigned int r = u + 0x7FFFu + ((u >> 16) & 1u);
    return (unsigned short)(r >> 16);
}

// K1: normalize pred rows -> bf16 predp[1024 rows][256 B], column-SWIZZLED:
// 16B slot s of row r holds linear slot (s ^ (r&7)).  Rows s>=20 are zeros.
__global__ __launch_bounds__(64) void k_prednorm(const float* __restrict__ pred,
                                                 unsigned int* __restrict__ predp) {
    int r = blockIdx.x;            // 0..1023 = b*32 + s
    int b = r >> 5, s = r & 31;
    int lane = threadIdx.x;        // 64 lanes x 2 floats
    int slot = (lane >> 2) ^ (r & 7);
    unsigned int* orow = predp + (size_t)r * 64;   // 64 u32 per row
    unsigned int val = 0u;
    if (s < SEQ) {
        float2 v = ((const float2*)(pred + (size_t)(b * SEQ + s) * DIM))[lane];
        float ss = v.x * v.x + v.y * v.y;
        #pragma unroll
        for (int d = 1; d < 64; d <<= 1) ss += __shfl_xor(ss, d);
        float sc = 1.0f / fmaxf(sqrtf(ss), 1e-8f);
        unsigned int lo = f2bf(v.x * sc);
        unsigned int hi = f2bf(v.y * sc);
        val = lo | (hi << 16);
    }
    orow[slot * 4 + (lane & 3)] = val;
}

// K2: fused  sim-max + exp + partial reductions.
// Block = 256 thr = 4 waves, each wave owns 32 songs.  predp LDS-staged in
// double-buffered 16KB chunks (2 b's each).  Per b: 8 ds_read_b128 (swizzled,
// conflict-free) + 16 mfma_16x16x32_bf16, then per-song max -> e^{s*x}, e^y,
// e^{y+s*x} butterfly-summed -> 3 partials per (b, wave).
__global__ __launch_bounds__(256, 3) void k_simfused(
        const float* __restrict__ song,
        const unsigned int* __restrict__ predp,
        const float* __restrict__ x_inv,
        const float* __restrict__ y,
        float* __restrict__ pZ, float* __restrict__ pY, float* __restrict__ pU) {
    int tid  = threadIdx.x;
    int lane = tid & 63;
    int wid  = tid >> 6;
    int l16  = lane & 15;
    int g    = lane >> 4;
    int song0 = blockIdx.x * 128 + wid * 32;
    int wv    = blockIdx.x * 4 + wid;

    // ---- song B-frags (2 groups of 16 songs), normalized on the fly ----
    int nA = song0 + l16, nB = song0 + 16 + l16;
    const float* sArow = song + (size_t)(nA < NS ? nA : NS - 1) * DIM;
    const float* sBrow = song + (size_t)(nB < NS ? nB : NS - 1) * DIM;
    float vA[4][8], vB[4][8];
    float ssA = 0.f, ssB = 0.f;
    #pragma unroll
    for (int kt = 0; kt < 4; ++kt) {
        int kb = kt * 32 + g * 8;
        float4 a0 = *(const float4*)(sArow + kb);
        float4 a1 = *(const float4*)(sArow + kb + 4);
        float4 b0 = *(const float4*)(sBrow + kb);
        float4 b1 = *(const float4*)(sBrow + kb + 4);
        vA[kt][0]=a0.x; vA[kt][1]=a0.y; vA[kt][2]=a0.z; vA[kt][3]=a0.w;
        vA[kt][4]=a1.x; vA[kt][5]=a1.y; vA[kt][6]=a1.z; vA[kt][7]=a1.w;
        vB[kt][0]=b0.x; vB[kt][1]=b0.y; vB[kt][2]=b0.z; vB[kt][3]=b0.w;
        vB[kt][4]=b1.x; vB[kt][5]=b1.y; vB[kt][6]=b1.z; vB[kt][7]=b1.w;
        #pragma unroll
        for (int j = 0; j < 8; ++j) { ssA += vA[kt][j]*vA[kt][j]; ssB += vB[kt][j]*vB[kt][j]; }
    }
    ssA += __shfl_xor(ssA, 16); ssA += __shfl_xor(ssA, 32);
    ssB += __shfl_xor(ssB, 16); ssB += __shfl_xor(ssB, 32);
    float scA = 1.0f / fmaxf(sqrtf(ssA), 1e-8f);
    float scB = 1.0f / fmaxf(sqrtf(ssB), 1e-8f);
    short8 bfA[4], bfB[4];
    #pragma unroll
    for (int kt = 0; kt < 4; ++kt)
        #pragma unroll
        for (int j = 0; j < 8; ++j) {
            bfA[kt][j] = (short)f2bf(vA[kt][j] * scA);
            bfB[kt][j] = (short)f2bf(vB[kt][j] * scB);
        }

    // ---- LDS double buffer: 2 x 16KB (2 b's per chunk) ----
    __shared__ char smem[32768];
    const char* psrc = (const char*)predp;
    int soff = wid * 1024 + lane * 16;   // per-lane src offset within 4KB pass

    // prologue: stage chunk 0 into buf0
    {
        const char* s0 = psrc;
        char* d0 = smem;
        #pragma unroll
        for (int i = 0; i < 4; ++i)
            __builtin_amdgcn_global_load_lds((g_u32*)(s0 + i * 4096 + soff),
                                             (l_u32*)(d0 + i * 4096 + wid * 1024),
                                             16, 0, 0);
    }
    __syncthreads();

    int n32  = song0 + (lane & 31);
    bool valid = (lane < 32) && (n32 < NS);
    size_t xyoff_base = valid ? (size_t)n32 : 0;

    int swz = (l16 & 7) << 4;    // row-swizzle key (same for row l16 and l16+16)

    #pragma unroll 2
    for (int c = 0; c < 16; ++c) {
        const char* buf = smem + (c & 1) * 16384;
        if (c < 15) {
            const char* sc_ = psrc + (c + 1) * 16384;
            char* dc = smem + ((c + 1) & 1) * 16384;
            #pragma unroll
            for (int i = 0; i < 4; ++i)
                __builtin_amdgcn_global_load_lds((g_u32*)(sc_ + i * 4096 + soff),
                                                 (l_u32*)(dc + i * 4096 + wid * 1024),
                                                 16, 0, 0);
        }
        #pragma unroll
        for (int bb = 0; bb < 2; ++bb) {
            int b = c * 2 + bb;
            // prefetch x/y early (independent of MFMAs)
            size_t xybase = (size_t)b * NS + xyoff_base;
            float xv = valid ? x_inv[xybase] : 0.f;
            float yv = valid ? y[xybase] : 0.f;

            f32x4 a00 = {0.f,0.f,0.f,0.f}, a01 = {0.f,0.f,0.f,0.f};
            f32x4 a10 = {0.f,0.f,0.f,0.f}, a11 = {0.f,0.f,0.f,0.f};
            const char* r0 = buf + (bb * 32 + l16) * 256;
            const char* r1 = r0 + 16 * 256;
            #pragma unroll
            for (int kt = 0; kt < 4; ++kt) {
                int so = (((kt * 4 + g) << 4) ^ swz);
                short8 f0 = *(const short8*)(r0 + so);
                short8 f1 = *(const short8*)(r1 + so);
                a00 = __builtin_amdgcn_mfma_f32_16x16x32_bf16(f0, bfA[kt], a00, 0, 0, 0);
                a01 = __builtin_amdgcn_mfma_f32_16x16x32_bf16(f1, bfA[kt], a01, 0, 0, 0);
                a10 = __builtin_amdgcn_mfma_f32_16x16x32_bf16(f0, bfB[kt], a10, 0, 0, 0);
                a11 = __builtin_amdgcn_mfma_f32_16x16x32_bf16(f1, bfB[kt], a11, 0, 0, 0);
            }
            // rows 0..15 in a00/a10 all real; rows 16..19 live in g==0 of a01/a11
            float mA = fmaxf(fmaxf(a00[0], a00[1]), fmaxf(a00[2], a00[3]));
            float mB = fmaxf(fmaxf(a10[0], a10[1]), fmaxf(a10[2], a10[3]));
            if (g == 0) {
                mA = fmaxf(mA, fmaxf(fmaxf(a01[0], a01[1]), fmaxf(a01[2], a01[3])));
                mB = fmaxf(mB, fmaxf(fmaxf(a11[0], a11[1]), fmaxf(a11[2], a11[3])));
            }
            mA = fmaxf(mA, __shfl_xor(mA, 16)); mA = fmaxf(mA, __shfl_xor(mA, 32));
            mB = fmaxf(mB, __shfl_xor(mB, 16)); mB = fmaxf(mB, __shfl_xor(mB, 32));

            float s  = (lane & 16) ? mB : mA;      // lanes 0-15: groupA, 16-31: groupB
            float es = valid ? __expf(s * xv) : 0.f;
            float ey = valid ? __expf(yv) : 0.f;
            float eu = es * ey;
            #pragma unroll
            for (int d = 1; d < 32; d <<= 1) {
                es += __shfl_xor(es, d);
                ey += __shfl_xor(ey, d);
                eu += __shfl_xor(eu, d);
            }
            if (lane == 0) {
                size_t pi = (size_t)b * PW + wv;
                pZ[pi] = es; pY[pi] = ey; pU[pi] = eu;
            }
        }
        __syncthreads();
    }
}

// K3: per-b combine partials -> loss_b = log(N+1) - U/(YZ*Z)
__global__ __launch_bounds__(256) void k_reduce(const float* __restrict__ pZ,
                                                const float* __restrict__ pY,
                                                const float* __restrict__ pU,
                                                float* __restrict__ lb) {
    int b = blockIdx.x, tid = threadIdx.x;
    float z = 0.f, yz = 0.f, u = 0.f;
    for (int i = tid; i < NWAVES; i += 256) {
        size_t pi = (size_t)b * PW + i;
        z += pZ[pi]; yz += pY[pi]; u += pU[pi];
    }
    #pragma unroll
    for (int d = 1; d < 64; d <<= 1) {
        z += __shfl_xor(z, d); yz += __shfl_xor(yz, d); u += __shfl_xor(u, d);
    }
    __shared__ float sz[4], sy[4], su[4];
    int w = tid >> 6;
    if ((tid & 63) == 0) { sz[w] = z; sy[w] = yz; su[w] = u; }
    __syncthreads();
    if (tid == 0) {
        float Z = sz[0] + sz[1] + sz[2] + sz[3];
        float Y = sy[0] + sy[1] + sy[2] + sy[3];
        float U = su[0] + su[1] + su[2] + su[3];
        lb[b] = logf((float)(NS + 1)) - U / (Y * Z);
    }
}

// K4: mean over b
__global__ __launch_bounds__(64) void k_final(const float* __restrict__ lb,
                                              float* __restrict__ out) {
    int lane = threadIdx.x;
    float v = (lane < BATCH) ? lb[lane] : 0.f;
    #pragma unroll
    for (int d = 1; d < 64; d <<= 1) v += __shfl_xor(v, d);
    if (lane == 0) out[0] = v * (1.0f / BATCH);
}

extern "C" void kernel_launch(void* const* d_in, const int* in_sizes, int n_in,
                              void* d_out, int out_size, void* d_ws, size_t ws_size,
                              hipStream_t stream) {
    const float* pred  = (const float*)d_in[0];
    const float* song  = (const float*)d_in[1];
    const float* x_inv = (const float*)d_in[2];
    const float* y     = (const float*)d_in[3];
    float* out = (float*)d_out;

    char* ws = (char*)d_ws;
    unsigned int* predp = (unsigned int*)ws;             // 256 KiB
    float* pZ = (float*)(ws + 262144);                   // 32*3136*4 = 401408
    float* pY = (float*)(ws + 262144 + 401408);
    float* pU = (float*)(ws + 262144 + 2 * 401408);
    float* lb = (float*)(ws + 262144 + 3 * 401408);

    k_prednorm<<<BATCH * 32, 64, 0, stream>>>(pred, predp);
    k_simfused<<<NBLK, 256, 0, stream>>>(song, predp, x_inv, y, pZ, pY, pU);
    k_reduce<<<BATCH, 256, 0, stream>>>(pZ, pY, pU, lb);
    k_final<<<1, 64, 0, stream>>>(lb, out);
}

// Round 3
// 71.687 us; speedup vs baseline: 3.2843x; 1.0898x over previous
//
#include <hip/hip_runtime.h>

typedef __attribute__((ext_vector_type(8))) short short8;
typedef __attribute__((ext_vector_type(4))) float f32x4;

#define NS    100000
#define DIM   128
#define BATCH 32
#define SEQ   20
#define NBLK  782              /* ceil(100000 / 128) */
#define PSTRIDE 800

typedef const __attribute__((address_space(1))) unsigned int g_u32;
typedef __attribute__((address_space(3))) unsigned int l_u32;

__device__ __forceinline__ unsigned short f2bf(float f) {
    unsigned int u = __float_as_uint(f);
    unsigned int r = u + 0x7FFFu + ((u >> 16) & 1u);
    return (unsigned short)(r >> 16);
}
__device__ __forceinline__ float bf2f_lo(unsigned int v) {
    return __uint_as_float(v << 16);
}
__device__ __forceinline__ float bf2f_hi(unsigned int v) {
    return __uint_as_float(v & 0xFFFF0000u);
}

// K1: normalize pred rows -> bf16 predp[1024 rows][256 B], 16B-slot swizzled
// (slot s of row r holds linear slot s ^ (r&7)). Rows s>=20 zero.
__global__ __launch_bounds__(64) void k_prednorm(const float* __restrict__ pred,
                                                 unsigned int* __restrict__ predp) {
    int r = blockIdx.x;            // 0..1023 = b*32 + s
    int b = r >> 5, s = r & 31;
    int lane = threadIdx.x;
    int slot = (lane >> 2) ^ (r & 7);
    unsigned int* orow = predp + (size_t)r * 64;
    unsigned int val = 0u;
    if (s < SEQ) {
        float2 v = ((const float2*)(pred + (size_t)(b * SEQ + s) * DIM))[lane];
        float ss = v.x * v.x + v.y * v.y;
        #pragma unroll
        for (int d = 1; d < 64; d <<= 1) ss += __shfl_xor(ss, d);
        float sc = 1.0f / fmaxf(sqrtf(ss), 1e-8f);
        val = (unsigned int)f2bf(v.x * sc) | ((unsigned int)f2bf(v.y * sc) << 16);
    }
    orow[slot * 4 + (lane & 3)] = val;
}

// K_ysum: yp[b*8+c] = sum over chunk c of exp(y[b,n])
__global__ __launch_bounds__(256) void k_ysum(const float* __restrict__ y,
                                              float* __restrict__ yp) {
    int b = blockIdx.x >> 3, c = blockIdx.x & 7;
    int tid = threadIdx.x;
    const float4* y4 = (const float4*)(y + (size_t)b * NS + (size_t)c * 12500);
    float acc = 0.f;
    for (int i = tid; i < 3125; i += 256) {
        float4 v = y4[i];
        acc += __expf(v.x) + __expf(v.y) + __expf(v.z) + __expf(v.w);
    }
    #pragma unroll
    for (int d = 1; d < 64; d <<= 1) acc += __shfl_xor(acc, d);
    __shared__ float sp[4];
    if ((tid & 63) == 0) sp[tid >> 6] = acc;
    __syncthreads();
    if (tid == 0) yp[blockIdx.x] = sp[0] + sp[1] + sp[2] + sp[3];
}

// K2: fused sim-max + exp, per-lane LDS table, block reduction at end.
__global__ __launch_bounds__(256, 3) void k_simfused(
        const float* __restrict__ song,
        const unsigned int* __restrict__ predp,
        const float* __restrict__ x_inv,
        const float* __restrict__ y,
        float* __restrict__ pZ, float* __restrict__ pU) {
    int tid  = threadIdx.x;
    int lane = tid & 63;
    int wid  = tid >> 6;
    int l16  = lane & 15;
    int g    = lane >> 4;
    int song0 = blockIdx.x * 128 + wid * 32;

    // ---- song B-frags (2 groups of 16 songs), normalized on the fly ----
    int nA = song0 + l16, nB = song0 + 16 + l16;
    const float* sArow = song + (size_t)(nA < NS ? nA : NS - 1) * DIM;
    const float* sBrow = song + (size_t)(nB < NS ? nB : NS - 1) * DIM;
    float vA[4][8], vB[4][8];
    float ssA = 0.f, ssB = 0.f;
    #pragma unroll
    for (int kt = 0; kt < 4; ++kt) {
        int kb = kt * 32 + g * 8;
        float4 a0 = *(const float4*)(sArow + kb);
        float4 a1 = *(const float4*)(sArow + kb + 4);
        float4 b0 = *(const float4*)(sBrow + kb);
        float4 b1 = *(const float4*)(sBrow + kb + 4);
        vA[kt][0]=a0.x; vA[kt][1]=a0.y; vA[kt][2]=a0.z; vA[kt][3]=a0.w;
        vA[kt][4]=a1.x; vA[kt][5]=a1.y; vA[kt][6]=a1.z; vA[kt][7]=a1.w;
        vB[kt][0]=b0.x; vB[kt][1]=b0.y; vB[kt][2]=b0.z; vB[kt][3]=b0.w;
        vB[kt][4]=b1.x; vB[kt][5]=b1.y; vB[kt][6]=b1.z; vB[kt][7]=b1.w;
        #pragma unroll
        for (int j = 0; j < 8; ++j) { ssA += vA[kt][j]*vA[kt][j]; ssB += vB[kt][j]*vB[kt][j]; }
    }
    ssA += __shfl_xor(ssA, 16); ssA += __shfl_xor(ssA, 32);
    ssB += __shfl_xor(ssB, 16); ssB += __shfl_xor(ssB, 32);
    float scA = 1.0f / fmaxf(sqrtf(ssA), 1e-8f);
    float scB = 1.0f / fmaxf(sqrtf(ssB), 1e-8f);
    short8 bfA[4], bfB[4];
    #pragma unroll
    for (int kt = 0; kt < 4; ++kt)
        #pragma unroll
        for (int j = 0; j < 8; ++j) {
            bfA[kt][j] = (short)f2bf(vA[kt][j] * scA);
            bfB[kt][j] = (short)f2bf(vB[kt][j] * scB);
        }

    __shared__ char stage[32768];          // double-buffered 2 x 16KB (2 b's each)
    __shared__ unsigned int accP[BATCH * 128];   // 16KB: per-(b, song-slot) packed bf16
    const char* psrc = (const char*)predp;
    int soff = wid * 1024 + lane * 16;

    #pragma unroll
    for (int i = 0; i < 4; ++i)
        __builtin_amdgcn_global_load_lds((g_u32*)(psrc + i * 4096 + soff),
                                         (l_u32*)(stage + i * 4096 + wid * 1024),
                                         16, 0, 0);
    __syncthreads();

    int n32 = song0 + (lane & 31);
    bool valid = (lane < 32) && (n32 < NS);
    size_t xyoff = valid ? (size_t)n32 : (size_t)0;
    int swz = (l16 & 7) << 4;
    int accslot = wid * 32 + (lane & 31);

    #pragma unroll 1
    for (int c = 0; c < 16; ++c) {
        const char* buf = stage + (c & 1) * 16384;
        if (c < 15) {
            const char* sc_ = psrc + (c + 1) * 16384;
            char* dc = stage + ((c + 1) & 1) * 16384;
            #pragma unroll
            for (int i = 0; i < 4; ++i)
                __builtin_amdgcn_global_load_lds((g_u32*)(sc_ + i * 4096 + soff),
                                                 (l_u32*)(dc + i * 4096 + wid * 1024),
                                                 16, 0, 0);
        }
        int b0 = c * 2, b1 = c * 2 + 1;
        float xv0 = x_inv[(size_t)b0 * NS + xyoff];
        float yv0 = y[(size_t)b0 * NS + xyoff];
        float xv1 = x_inv[(size_t)b1 * NS + xyoff];
        float yv1 = y[(size_t)b1 * NS + xyoff];

        f32x4 p00 = {0,0,0,0}, p01 = {0,0,0,0}, p10 = {0,0,0,0}, p11 = {0,0,0,0};
        f32x4 q00 = {0,0,0,0}, q01 = {0,0,0,0}, q10 = {0,0,0,0}, q11 = {0,0,0,0};
        const char* r0a = buf + l16 * 256;
        const char* r1a = r0a + 16 * 256;
        const char* r0b = buf + (32 + l16) * 256;
        const char* r1b = r0b + 16 * 256;
        #pragma unroll
        for (int kt = 0; kt < 4; ++kt) {
            int so = (((kt * 4 + g) << 4) ^ swz);
            short8 f0 = *(const short8*)(r0a + so);
            short8 f1 = *(const short8*)(r1a + so);
            short8 h0 = *(const short8*)(r0b + so);
            short8 h1 = *(const short8*)(r1b + so);
            p00 = __builtin_amdgcn_mfma_f32_16x16x32_bf16(f0, bfA[kt], p00, 0, 0, 0);
            p01 = __builtin_amdgcn_mfma_f32_16x16x32_bf16(f1, bfA[kt], p01, 0, 0, 0);
            p10 = __builtin_amdgcn_mfma_f32_16x16x32_bf16(f0, bfB[kt], p10, 0, 0, 0);
            p11 = __builtin_amdgcn_mfma_f32_16x16x32_bf16(f1, bfB[kt], p11, 0, 0, 0);
            q00 = __builtin_amdgcn_mfma_f32_16x16x32_bf16(h0, bfA[kt], q00, 0, 0, 0);
            q01 = __builtin_amdgcn_mfma_f32_16x16x32_bf16(h1, bfA[kt], q01, 0, 0, 0);
            q10 = __builtin_amdgcn_mfma_f32_16x16x32_bf16(h0, bfB[kt], q10, 0, 0, 0);
            q11 = __builtin_amdgcn_mfma_f32_16x16x32_bf16(h1, bfB[kt], q11, 0, 0, 0);
        }
        // ---- epilogue b0 ----
        {
            float mA = fmaxf(fmaxf(p00[0], p00[1]), fmaxf(p00[2], p00[3]));
            float mB = fmaxf(fmaxf(p10[0], p10[1]), fmaxf(p10[2], p10[3]));
            if (g == 0) {
                mA = fmaxf(mA, fmaxf(fmaxf(p01[0], p01[1]), fmaxf(p01[2], p01[3])));
                mB = fmaxf(mB, fmaxf(fmaxf(p11[0], p11[1]), fmaxf(p11[2], p11[3])));
            }
            mA = fmaxf(mA, __shfl_xor(mA, 16)); mA = fmaxf(mA, __shfl_xor(mA, 32));
            mB = fmaxf(mB, __shfl_xor(mB, 16)); mB = fmaxf(mB, __shfl_xor(mB, 32));
            float s  = (lane & 16) ? mB : mA;
            float sx = s * xv0;
            float es = valid ? __expf(sx) : 0.f;
            float eu = valid ? __expf(sx + yv0) : 0.f;
            if (lane < 32)
                accP[b0 * 128 + accslot] =
                    (unsigned int)f2bf(es) | ((unsigned int)f2bf(eu) << 16);
        }
        // ---- epilogue b1 ----
        {
            float mA = fmaxf(fmaxf(q00[0], q00[1]), fmaxf(q00[2], q00[3]));
            float mB = fmaxf(fmaxf(q10[0], q10[1]), fmaxf(q10[2], q10[3]));
            if (g == 0) {
                mA = fmaxf(mA, fmaxf(fmaxf(q01[0], q01[1]), fmaxf(q01[2], q01[3])));
                mB = fmaxf(mB, fmaxf(fmaxf(q11[0], q11[1]), fmaxf(q11[2], q11[3])));
            }
            mA = fmaxf(mA, __shfl_xor(mA, 16)); mA = fmaxf(mA, __shfl_xor(mA, 32));
            mB = fmaxf(mB, __shfl_xor(mB, 16)); mB = fmaxf(mB, __shfl_xor(mB, 32));
            float s  = (lane & 16) ? mB : mA;
            float sx = s * xv1;
            float es = valid ? __expf(sx) : 0.f;
            float eu = valid ? __expf(sx + yv1) : 0.f;
            if (lane < 32)
                accP[b1 * 128 + accslot] =
                    (unsigned int)f2bf(es) | ((unsigned int)f2bf(eu) << 16);
        }
        __syncthreads();
    }

    // ---- block reduction: accP[32][128] -> per-b (Z,U) partials ----
    int rb = tid >> 3, rj = tid & 7;
    float Z = 0.f, U = 0.f;
    #pragma unroll
    for (int i = 0; i < 16; ++i) {
        unsigned int v = accP[rb * 128 + rj + 8 * i];
        Z += bf2f_lo(v);
        U += bf2f_hi(v);
    }
    #pragma unroll
    for (int d = 1; d < 8; d <<= 1) {
        Z += __shfl_xor(Z, d);
        U += __shfl_xor(U, d);
    }
    if (rj == 0) {
        pZ[(size_t)rb * PSTRIDE + blockIdx.x] = Z;
        pU[(size_t)rb * PSTRIDE + blockIdx.x] = U;
    }
}

// K3: per-b combine partials -> loss_b = log(N+1) - U/(Y*Z)
__global__ __launch_bounds__(256) void k_reduce(const float* __restrict__ pZ,
                                                const float* __restrict__ pU,
                                                const float* __restrict__ yp,
                                                float* __restrict__ lb) {
    int b = blockIdx.x, tid = threadIdx.x;
    float z = 0.f, u = 0.f;
    for (int i = tid; i < NBLK; i += 256) {
        z += pZ[(size_t)b * PSTRIDE + i];
        u += pU[(size_t)b * PSTRIDE + i];
    }
    #pragma unroll
    for (int d = 1; d < 64; d <<= 1) { z += __shfl_xor(z, d); u += __shfl_xor(u, d); }
    __shared__ float sz[4], su[4];
    int w = tid >> 6;
    if ((tid & 63) == 0) { sz[w] = z; su[w] = u; }
    __syncthreads();
    if (tid == 0) {
        float Z = sz[0] + sz[1] + sz[2] + sz[3];
        float U = su[0] + su[1] + su[2] + su[3];
        float Y = 0.f;
        #pragma unroll
        for (int j = 0; j < 8; ++j) Y += yp[b * 8 + j];
        lb[b] = logf((float)(NS + 1)) - U / (Y * Z);
    }
}

// K4: mean over b
__global__ __launch_bounds__(64) void k_final(const float* __restrict__ lb,
                                              float* __restrict__ out) {
    int lane = threadIdx.x;
    float v = (lane < BATCH) ? lb[lane] : 0.f;
    #pragma unroll
    for (int d = 1; d < 64; d <<= 1) v += __shfl_xor(v, d);
    if (lane == 0) out[0] = v * (1.0f / BATCH);
}

extern "C" void kernel_launch(void* const* d_in, const int* in_sizes, int n_in,
                              void* d_out, int out_size, void* d_ws, size_t ws_size,
                              hipStream_t stream) {
    const float* pred  = (const float*)d_in[0];
    const float* song  = (const float*)d_in[1];
    const float* x_inv = (const float*)d_in[2];
    const float* y     = (const float*)d_in[3];
    float* out = (float*)d_out;

    char* ws = (char*)d_ws;
    unsigned int* predp = (unsigned int*)ws;                       // 256 KiB
    float* yp = (float*)(ws + 262144);                             // 1 KiB
    float* pZ = (float*)(ws + 263168);                             // 32*800*4 = 100 KiB
    float* pU = (float*)(ws + 263168 + 102400);
    float* lb = (float*)(ws + 263168 + 2 * 102400);

    k_prednorm<<<BATCH * 32, 64, 0, stream>>>(pred, predp);
    k_ysum<<<BATCH * 8, 256, 0, stream>>>(y, yp);
    k_simfused<<<NBLK, 256, 0, stream>>>(song, predp, x_inv, y, pZ, pU);
    k_reduce<<<BATCH, 256, 0, stream>>>(pZ, pU, yp, lb);
    k_final<<<1, 64, 0, stream>>>(lb, out);
}

// Round 4
// 66.396 us; speedup vs baseline: 3.5460x; 1.0797x over previous
//
#include <hip/hip_runtime.h>

typedef __attribute__((ext_vector_type(8))) short short8;
typedef __attribute__((ext_vector_type(4))) float f32x4;

#define NS    100000
#define DIM   128
#define BATCH 32
#define SEQ   20
#define NBLK  782              /* ceil(100000 / 128) */
#define PSTRIDE 800

typedef const __attribute__((address_space(1))) unsigned int g_u32;
typedef __attribute__((address_space(3))) unsigned int l_u32;

__device__ __forceinline__ unsigned short f2bf(float f) {
    unsigned int u = __float_as_uint(f);
    unsigned int r = u + 0x7FFFu + ((u >> 16) & 1u);
    return (unsigned short)(r >> 16);
}
__device__ __forceinline__ float bf2f_lo(unsigned int v) { return __uint_as_float(v << 16); }
__device__ __forceinline__ float bf2f_hi(unsigned int v) { return __uint_as_float(v & 0xFFFF0000u); }

// K1: normalize pred rows -> bf16 predp[1024 rows][256 B], 16B-slot swizzled
// (slot s of row r holds linear slot s ^ (r&7)). Rows s>=20 zero.
__global__ __launch_bounds__(64) void k_prednorm(const float* __restrict__ pred,
                                                 unsigned int* __restrict__ predp) {
    int r = blockIdx.x;            // 0..1023 = b*32 + s
    int b = r >> 5, s = r & 31;
    int lane = threadIdx.x;
    int slot = (lane >> 2) ^ (r & 7);
    unsigned int* orow = predp + (size_t)r * 64;
    unsigned int val = 0u;
    if (s < SEQ) {
        float2 v = ((const float2*)(pred + (size_t)(b * SEQ + s) * DIM))[lane];
        float ss = v.x * v.x + v.y * v.y;
        #pragma unroll
        for (int d = 1; d < 64; d <<= 1) ss += __shfl_xor(ss, d);
        float sc = 1.0f / fmaxf(sqrtf(ss), 1e-8f);
        val = (unsigned int)f2bf(v.x * sc) | ((unsigned int)f2bf(v.y * sc) << 16);
    }
    orow[slot * 4 + (lane & 3)] = val;
}

// K_ysum: yp[b*8+c] = sum over chunk c of exp(y[b,n])
__global__ __launch_bounds__(256) void k_ysum(const float* __restrict__ y,
                                              float* __restrict__ yp) {
    int b = blockIdx.x >> 3, c = blockIdx.x & 7;
    int tid = threadIdx.x;
    const float4* y4 = (const float4*)(y + (size_t)b * NS + (size_t)c * 12500);
    float acc = 0.f;
    for (int i = tid; i < 3125; i += 256) {
        float4 v = y4[i];
        acc += __expf(v.x) + __expf(v.y) + __expf(v.z) + __expf(v.w);
    }
    #pragma unroll
    for (int d = 1; d < 64; d <<= 1) acc += __shfl_xor(acc, d);
    __shared__ float sp[4];
    if ((tid & 63) == 0) sp[tid >> 6] = acc;
    __syncthreads();
    if (tid == 0) yp[blockIdx.x] = sp[0] + sp[1] + sp[2] + sp[3];
}

// K2: fused sim-max + exp with compile-time ping-pong LDS double buffer.
__global__ __launch_bounds__(256, 3) void k_simfused(
        const float* __restrict__ song,
        const unsigned int* __restrict__ predp,
        const float* __restrict__ x_inv,
        const float* __restrict__ y,
        float* __restrict__ pZ, float* __restrict__ pU) {
    int tid  = threadIdx.x;
    int lane = tid & 63;
    int wid  = tid >> 6;
    int l16  = lane & 15;
    int g    = lane >> 4;
    int song0 = blockIdx.x * 128 + wid * 32;

    // ---- song B-frags (2 groups of 16 songs), normalized on the fly ----
    int nA = song0 + l16, nB = song0 + 16 + l16;
    const float* sArow = song + (size_t)(nA < NS ? nA : NS - 1) * DIM;
    const float* sBrow = song + (size_t)(nB < NS ? nB : NS - 1) * DIM;
    float vA[4][8], vB[4][8];
    float ssA = 0.f, ssB = 0.f;
    #pragma unroll
    for (int kt = 0; kt < 4; ++kt) {
        int kb = kt * 32 + g * 8;
        float4 a0 = *(const float4*)(sArow + kb);
        float4 a1 = *(const float4*)(sArow + kb + 4);
        float4 b0 = *(const float4*)(sBrow + kb);
        float4 b1 = *(const float4*)(sBrow + kb + 4);
        vA[kt][0]=a0.x; vA[kt][1]=a0.y; vA[kt][2]=a0.z; vA[kt][3]=a0.w;
        vA[kt][4]=a1.x; vA[kt][5]=a1.y; vA[kt][6]=a1.z; vA[kt][7]=a1.w;
        vB[kt][0]=b0.x; vB[kt][1]=b0.y; vB[kt][2]=b0.z; vB[kt][3]=b0.w;
        vB[kt][4]=b1.x; vB[kt][5]=b1.y; vB[kt][6]=b1.z; vB[kt][7]=b1.w;
        #pragma unroll
        for (int j = 0; j < 8; ++j) { ssA += vA[kt][j]*vA[kt][j]; ssB += vB[kt][j]*vB[kt][j]; }
    }
    ssA += __shfl_xor(ssA, 16); ssA += __shfl_xor(ssA, 32);
    ssB += __shfl_xor(ssB, 16); ssB += __shfl_xor(ssB, 32);
    float scA = 1.0f / fmaxf(sqrtf(ssA), 1e-8f);
    float scB = 1.0f / fmaxf(sqrtf(ssB), 1e-8f);
    short8 bfA[4], bfB[4];
    #pragma unroll
    for (int kt = 0; kt < 4; ++kt)
        #pragma unroll
        for (int j = 0; j < 8; ++j) {
            bfA[kt][j] = (short)f2bf(vA[kt][j] * scA);
            bfB[kt][j] = (short)f2bf(vB[kt][j] * scB);
        }

    // ---- two DISTINCT LDS buffers: compile-time ping-pong ----
    __shared__ char stageA[16384];
    __shared__ char stageB[16384];
    __shared__ unsigned int accP[BATCH * 128];   // 16KB packed bf16 (Z,U)
    const char* psrc = (const char*)predp;
    int soff = wid * 1024 + lane * 16;

    auto stage_to = [&](char* dst, int chunk) {
        const char* s = psrc + (size_t)chunk * 16384;
        #pragma unroll
        for (int i = 0; i < 4; ++i)
            __builtin_amdgcn_global_load_lds((g_u32*)(s + i * 4096 + soff),
                                             (l_u32*)(dst + i * 4096 + wid * 1024),
                                             16, 0, 0);
    };

    int n32 = song0 + (lane & 31);
    bool valid = (lane < 32) && (n32 < NS);
    size_t xyoff = valid ? (size_t)n32 : (size_t)0;
    int swz = (l16 & 7) << 4;
    int accslot = wid * 32 + (lane & 31);

    // prologue: stage chunk 0, prefetch x/y for pair (0,1)
    stage_to(stageA, 0);
    float xv0 = x_inv[xyoff];
    float yv0 = y[xyoff];
    float xv1 = x_inv[(size_t)NS + xyoff];
    float yv1 = y[(size_t)NS + xyoff];
    __syncthreads();

    auto epi = [&](const f32x4& p00, const f32x4& p01, const f32x4& p10,
                   const f32x4& p11, float xv, float yv, int b) {
        float mA = fmaxf(fmaxf(p00[0], p00[1]), fmaxf(p00[2], p00[3]));
        float mB = fmaxf(fmaxf(p10[0], p10[1]), fmaxf(p10[2], p10[3]));
        if (g == 0) {
            mA = fmaxf(mA, fmaxf(fmaxf(p01[0], p01[1]), fmaxf(p01[2], p01[3])));
            mB = fmaxf(mB, fmaxf(fmaxf(p11[0], p11[1]), fmaxf(p11[2], p11[3])));
        }
        mA = fmaxf(mA, __shfl_xor(mA, 16)); mA = fmaxf(mA, __shfl_xor(mA, 32));
        mB = fmaxf(mB, __shfl_xor(mB, 16)); mB = fmaxf(mB, __shfl_xor(mB, 32));
        float s  = (lane & 16) ? mB : mA;
        float sx = s * xv;
        float es = valid ? __expf(sx) : 0.f;
        float eu = valid ? __expf(sx + yv) : 0.f;
        if (lane < 32)
            accP[b * 128 + accslot] =
                (unsigned int)f2bf(es) | ((unsigned int)f2bf(eu) << 16);
    };

    auto do_phase = [&](const char* bufR, char* bufW, int c) {
        int b0 = 2 * c, b1 = 2 * c + 1;
        // 1) A-fragment ds_reads FIRST (no vmem issued yet this phase)
        short8 f0[4], f1[4], h0[4], h1[4];
        const char* r0a = bufR + l16 * 256;
        const char* r1a = r0a + 16 * 256;
        const char* r0b = bufR + (32 + l16) * 256;
        const char* r1b = r0b + 16 * 256;
        #pragma unroll
        for (int kt = 0; kt < 4; ++kt) {
            int so = (((kt * 4 + g) << 4) ^ swz);
            f0[kt] = *(const short8*)(r0a + so);
            f1[kt] = *(const short8*)(r1a + so);
            h0[kt] = *(const short8*)(r0b + so);
            h1[kt] = *(const short8*)(r1b + so);
        }
        // 2) issue next-chunk stage into the OTHER buffer (distinct array)
        if (c < 15) stage_to(bufW, c + 1);
        // 3) issue x/y register-prefetch for the NEXT pair
        float nx0 = xv0, ny0 = yv0, nx1 = xv1, ny1 = yv1;
        if (c < 15) {
            nx0 = x_inv[(size_t)(b0 + 2) * NS + xyoff];
            ny0 = y[(size_t)(b0 + 2) * NS + xyoff];
            nx1 = x_inv[(size_t)(b1 + 2) * NS + xyoff];
            ny1 = y[(size_t)(b1 + 2) * NS + xyoff];
        }
        // 4) MFMAs
        f32x4 p00 = {0,0,0,0}, p01 = {0,0,0,0}, p10 = {0,0,0,0}, p11 = {0,0,0,0};
        f32x4 q00 = {0,0,0,0}, q01 = {0,0,0,0}, q10 = {0,0,0,0}, q11 = {0,0,0,0};
        #pragma unroll
        for (int kt = 0; kt < 4; ++kt) {
            p00 = __builtin_amdgcn_mfma_f32_16x16x32_bf16(f0[kt], bfA[kt], p00, 0, 0, 0);
            p01 = __builtin_amdgcn_mfma_f32_16x16x32_bf16(f1[kt], bfA[kt], p01, 0, 0, 0);
            p10 = __builtin_amdgcn_mfma_f32_16x16x32_bf16(f0[kt], bfB[kt], p10, 0, 0, 0);
            p11 = __builtin_amdgcn_mfma_f32_16x16x32_bf16(f1[kt], bfB[kt], p11, 0, 0, 0);
            q00 = __builtin_amdgcn_mfma_f32_16x16x32_bf16(h0[kt], bfA[kt], q00, 0, 0, 0);
            q01 = __builtin_amdgcn_mfma_f32_16x16x32_bf16(h1[kt], bfA[kt], q01, 0, 0, 0);
            q10 = __builtin_amdgcn_mfma_f32_16x16x32_bf16(h0[kt], bfB[kt], q10, 0, 0, 0);
            q11 = __builtin_amdgcn_mfma_f32_16x16x32_bf16(h1[kt], bfB[kt], q11, 0, 0, 0);
        }
        // 5) epilogues with PREVIOUSLY prefetched x/y
        epi(p00, p01, p10, p11, xv0, yv0, b0);
        epi(q00, q01, q10, q11, xv1, yv1, b1);
        xv0 = nx0; yv0 = ny0; xv1 = nx1; yv1 = ny1;
        __syncthreads();
    };

    #pragma unroll 1
    for (int cc = 0; cc < 8; ++cc) {
        do_phase(stageA, stageB, 2 * cc);
        do_phase(stageB, stageA, 2 * cc + 1);
    }

    // ---- block reduction: accP[32][128] -> per-b (Z,U) partials ----
    int rb = tid >> 3, rj = tid & 7;
    float Z = 0.f, U = 0.f;
    #pragma unroll
    for (int i = 0; i < 16; ++i) {
        unsigned int v = accP[rb * 128 + rj + 8 * i];
        Z += bf2f_lo(v);
        U += bf2f_hi(v);
    }
    #pragma unroll
    for (int d = 1; d < 8; d <<= 1) {
        Z += __shfl_xor(Z, d);
        U += __shfl_xor(U, d);
    }
    if (rj == 0) {
        pZ[(size_t)rb * PSTRIDE + blockIdx.x] = Z;
        pU[(size_t)rb * PSTRIDE + blockIdx.x] = U;
    }
}

// K3: per-b combine partials -> loss_b = log(N+1) - U/(Y*Z)
__global__ __launch_bounds__(256) void k_reduce(const float* __restrict__ pZ,
                                                const float* __restrict__ pU,
                                                const float* __restrict__ yp,
                                                float* __restrict__ lb) {
    int b = blockIdx.x, tid = threadIdx.x;
    float z = 0.f, u = 0.f;
    for (int i = tid; i < NBLK; i += 256) {
        z += pZ[(size_t)b * PSTRIDE + i];
        u += pU[(size_t)b * PSTRIDE + i];
    }
    #pragma unroll
    for (int d = 1; d < 64; d <<= 1) { z += __shfl_xor(z, d); u += __shfl_xor(u, d); }
    __shared__ float sz[4], su[4];
    int w = tid >> 6;
    if ((tid & 63) == 0) { sz[w] = z; su[w] = u; }
    __syncthreads();
    if (tid == 0) {
        float Z = sz[0] + sz[1] + sz[2] + sz[3];
        float U = su[0] + su[1] + su[2] + su[3];
        float Y = 0.f;
        #pragma unroll
        for (int j = 0; j < 8; ++j) Y += yp[b * 8 + j];
        lb[b] = logf((float)(NS + 1)) - U / (Y * Z);
    }
}

// K4: mean over b
__global__ __launch_bounds__(64) void k_final(const float* __restrict__ lb,
                                              float* __restrict__ out) {
    int lane = threadIdx.x;
    float v = (lane < BATCH) ? lb[lane] : 0.f;
    #pragma unroll
    for (int d = 1; d < 64; d <<= 1) v += __shfl_xor(v, d);
    if (lane == 0) out[0] = v * (1.0f / BATCH);
}

extern "C" void kernel_launch(void* const* d_in, const int* in_sizes, int n_in,
                              void* d_out, int out_size, void* d_ws, size_t ws_size,
                              hipStream_t stream) {
    const float* pred  = (const float*)d_in[0];
    const float* song  = (const float*)d_in[1];
    const float* x_inv = (const float*)d_in[2];
    const float* y     = (const float*)d_in[3];
    float* out = (float*)d_out;

    char* ws = (char*)d_ws;
    unsigned int* predp = (unsigned int*)ws;                       // 256 KiB
    float* yp = (float*)(ws + 262144);                             // 1 KiB
    float* pZ = (float*)(ws + 263168);                             // 32*800*4 = 100 KiB
    float* pU = (float*)(ws + 263168 + 102400);
    float* lb = (float*)(ws + 263168 + 2 * 102400);

    k_prednorm<<<BATCH * 32, 64, 0, stream>>>(pred, predp);
    k_ysum<<<BATCH * 8, 256, 0, stream>>>(y, yp);
    k_simfused<<<NBLK, 256, 0, stream>>>(song, predp, x_inv, y, pZ, pU);
    k_reduce<<<BATCH, 256, 0, stream>>>(pZ, pU, yp, lb);
    k_final<<<1, 64, 0, stream>>>(lb, out);
}

// Round 5
// 64.956 us; speedup vs baseline: 3.6247x; 1.0222x over previous
//
#include <hip/hip_runtime.h>

typedef __attribute__((ext_vector_type(8))) short short8;
typedef __attribute__((ext_vector_type(4))) float f32x4;
typedef __attribute__((ext_vector_type(4))) unsigned int u32x4;

#define NS    100000
#define DIM   128
#define BATCH 32
#define SEQ   20
#define NBLK  782              /* ceil(100000 / 128) */
#define PSTRIDE 800

__device__ __forceinline__ unsigned short f2bf(float f) {
    unsigned int u = __float_as_uint(f);
    unsigned int r = u + 0x7FFFu + ((u >> 16) & 1u);
    return (unsigned short)(r >> 16);
}

// K1: normalize pred rows -> bf16 predp[b][32 rows][128], linear layout.
// Only rows 0..19 are written (rows 20..31 never read).
__global__ __launch_bounds__(64) void k_prednorm(const float* __restrict__ pred,
                                                 unsigned short* __restrict__ predp) {
    int s = blockIdx.x, b = blockIdx.y;    // grid (20, 32)
    int lane = threadIdx.x;
    float2 v = ((const float2*)(pred + (size_t)(b * SEQ + s) * DIM))[lane];
    float ss = v.x * v.x + v.y * v.y;
    #pragma unroll
    for (int d = 1; d < 64; d <<= 1) ss += __shfl_xor(ss, d);
    float sc = 1.0f / fmaxf(sqrtf(ss), 1e-8f);
    unsigned int val = (unsigned int)f2bf(v.x * sc) | ((unsigned int)f2bf(v.y * sc) << 16);
    ((unsigned int*)(predp + ((size_t)b * 32 + s) * DIM))[lane] = val;
}

// K2: b-resident / song-streamed fused kernel.
// 8 waves x 4 b's = 32 b's per block; block owns 128 songs (4 chunks of 32).
// A-frags in registers (tail-rows of 4 b's packed into one 16-row tile).
// Songs: load f32 -> normalize -> swizzled LDS (2x8KB dbuf) -> B-frags.
// Epilogue: fmax tree + 2 shfl + 2 expf -> per-lane f32 accumulate Z/Y/U.
__global__ __launch_bounds__(512) void k_main(
        const float* __restrict__ song,
        const unsigned short* __restrict__ predp,
        const float* __restrict__ x_inv,
        const float* __restrict__ y,
        float* __restrict__ pZ, float* __restrict__ pU, float* __restrict__ pY) {
    const int tid  = threadIdx.x;
    const int lane = tid & 63;
    const int wid  = tid >> 6;          // 0..7
    const int l16  = lane & 15;
    const int g    = lane >> 4;         // 0..3
    const int song0 = blockIdx.x * 128;
    const int bq    = wid * 4;          // wave's batch quad

    // ---- A fragments (global predp, L2/L3-hot) ----
    short8 Am[4][4];                    // [b_local][kt], rows 0..15
    short8 At[4];                       // tail tile: row l16 -> b=bq+(l16>>2), s=16+(l16&3)
    #pragma unroll
    for (int bl = 0; bl < 4; ++bl)
        #pragma unroll
        for (int kt = 0; kt < 4; ++kt)
            Am[bl][kt] = *(const short8*)(predp + ((size_t)(bq + bl) * 32 + l16) * DIM + kt * 32 + g * 8);
    {
        int tb = bq + (l16 >> 2), ts = 16 + (l16 & 3);
        #pragma unroll
        for (int kt = 0; kt < 4; ++kt)
            At[kt] = *(const short8*)(predp + ((size_t)tb * 32 + ts) * DIM + kt * 32 + g * 8);
    }

    __shared__ u32x4 bufA_[512];        // 8KB: 32 song-rows x 256B, 16B-slot swizzled
    __shared__ u32x4 bufB_[512];
    char* const bufA = (char*)bufA_;
    char* const bufB = (char*)bufB_;

    const int srow = wid * 4 + (lane >> 4);     // chunk-local song row 0..31
    const int sel8 = lane & 15;                 // 16B slot within row
    char* const wrA = bufA + srow * 256 + ((sel8 ^ (srow & 7)) << 4);
    char* const wrB = bufB + srow * 256 + ((sel8 ^ (srow & 7)) << 4);

    float Z[4] = {0.f, 0.f, 0.f, 0.f};
    float U[4] = {0.f, 0.f, 0.f, 0.f};
    float Yv[4] = {0.f, 0.f, 0.f, 0.f};

    // ---- helpers (inlined manually via lambdas, all-static indices) ----
    auto load_songs = [&](int ch, float4& u0, float4& u1) {
        int n = song0 + ch * 32 + srow;
        n = n < NS ? n : NS - 1;
        const float* r = song + (size_t)n * DIM + sel8 * 8;
        u0 = *(const float4*)r;
        u1 = *(const float4*)(r + 4);
    };
    auto norm_write = [&](float4 u0, float4 u1, char* w) {
        float ss = u0.x*u0.x + u0.y*u0.y + u0.z*u0.z + u0.w*u0.w
                 + u1.x*u1.x + u1.y*u1.y + u1.z*u1.z + u1.w*u1.w;
        ss += __shfl_xor(ss, 1); ss += __shfl_xor(ss, 2);
        ss += __shfl_xor(ss, 4); ss += __shfl_xor(ss, 8);
        float sc = 1.0f / fmaxf(sqrtf(ss), 1e-8f);
        u32x4 o;
        o[0] = (unsigned int)f2bf(u0.x*sc) | ((unsigned int)f2bf(u0.y*sc) << 16);
        o[1] = (unsigned int)f2bf(u0.z*sc) | ((unsigned int)f2bf(u0.w*sc) << 16);
        o[2] = (unsigned int)f2bf(u1.x*sc) | ((unsigned int)f2bf(u1.y*sc) << 16);
        o[3] = (unsigned int)f2bf(u1.z*sc) | ((unsigned int)f2bf(u1.w*sc) << 16);
        *(u32x4*)w = o;
    };
    auto load_xy = [&](int ch, float* xv, float* yv) {
        int n = song0 + ch * 32 + (lane & 31);
        size_t off = (size_t)(n < NS ? n : 0);
        #pragma unroll
        for (int bl = 0; bl < 4; ++bl) {
            xv[bl] = x_inv[(size_t)(bq + bl) * NS + off];
            yv[bl] = y[(size_t)(bq + bl) * NS + off];
        }
    };

    // ---- prologue: stage chunk 0 ----
    float xv[4], yv[4];
    {
        float4 s0, s1;
        load_songs(0, s0, s1);
        load_xy(0, xv, yv);
        norm_write(s0, s1, wrA);
    }
    __syncthreads();

    #pragma unroll
    for (int ch = 0; ch < 4; ++ch) {
        const char* buf = (ch & 1) ? bufB : bufA;
        char* wnext     = (ch & 1) ? wrA : wrB;

        // prefetch next chunk (songs + x/y) early — hides HBM under MFMA
        float4 n0, n1;
        float nxv[4], nyv[4];
        if (ch < 3) {
            load_songs(ch + 1, n0, n1);
            load_xy(ch + 1, nxv, nyv);
        }

        // ---- MFMA: 40 per wave (4 main b's + packed tail) x 2 song-tiles ----
        f32x4 aM[4][2];
        f32x4 aT[2];
        #pragma unroll
        for (int bl = 0; bl < 4; ++bl) { aM[bl][0] = (f32x4){0,0,0,0}; aM[bl][1] = (f32x4){0,0,0,0}; }
        aT[0] = (f32x4){0,0,0,0}; aT[1] = (f32x4){0,0,0,0};

        #pragma unroll
        for (int kt = 0; kt < 4; ++kt) {
            int po = (((kt * 4 + g) ^ (l16 & 7)) << 4);
            short8 B0 = *(const short8*)(buf + l16 * 256 + po);
            short8 B1 = *(const short8*)(buf + (16 + l16) * 256 + po);
            #pragma unroll
            for (int bl = 0; bl < 4; ++bl) {
                aM[bl][0] = __builtin_amdgcn_mfma_f32_16x16x32_bf16(Am[bl][kt], B0, aM[bl][0], 0, 0, 0);
                aM[bl][1] = __builtin_amdgcn_mfma_f32_16x16x32_bf16(Am[bl][kt], B1, aM[bl][1], 0, 0, 0);
            }
            aT[0] = __builtin_amdgcn_mfma_f32_16x16x32_bf16(At[kt], B0, aT[0], 0, 0, 0);
            aT[1] = __builtin_amdgcn_mfma_f32_16x16x32_bf16(At[kt], B1, aT[1], 0, 0, 0);
        }

        // ---- epilogue: per-b max over 20 rows, exp, per-lane accumulate ----
        int nb = song0 + ch * 32 + (lane & 31);
        bool valid = (lane < 32) && (nb < NS);
        float mt0 = fmaxf(fmaxf(aT[0][0], aT[0][1]), fmaxf(aT[0][2], aT[0][3]));
        float mt1 = fmaxf(fmaxf(aT[1][0], aT[1][1]), fmaxf(aT[1][2], aT[1][3]));
        #pragma unroll
        for (int bl = 0; bl < 4; ++bl) {
            float m0 = fmaxf(fmaxf(aM[bl][0][0], aM[bl][0][1]), fmaxf(aM[bl][0][2], aM[bl][0][3]));
            float m1 = fmaxf(fmaxf(aM[bl][1][0], aM[bl][1][1]), fmaxf(aM[bl][1][2], aM[bl][1][3]));
            // tail rows (s=16..19) of b = bq+bl live in lane-group g==bl
            m0 = (g == bl) ? fmaxf(m0, mt0) : m0;
            m1 = (g == bl) ? fmaxf(m1, mt1) : m1;
            m0 = fmaxf(m0, __shfl_xor(m0, 16)); m0 = fmaxf(m0, __shfl_xor(m0, 32));
            m1 = fmaxf(m1, __shfl_xor(m1, 16)); m1 = fmaxf(m1, __shfl_xor(m1, 32));
            float s  = (lane & 16) ? m1 : m0;   // lanes 0-15: songs l16; 16-31: 16+l16
            float es = valid ? __expf(s * xv[bl]) : 0.f;
            float ey = valid ? __expf(yv[bl]) : 0.f;
            Z[bl]  += es;
            Yv[bl] += ey;
            U[bl]  += es * ey;
        }

        // ---- stage next chunk, rotate prefetch ----
        if (ch < 3) {
            norm_write(n0, n1, wnext);
            #pragma unroll
            for (int bl = 0; bl < 4; ++bl) { xv[bl] = nxv[bl]; yv[bl] = nyv[bl]; }
            __syncthreads();
        }
    }

    // ---- wave reduce (lanes 0..31 hold all contributions) + write partials ----
    #pragma unroll
    for (int d = 1; d < 32; d <<= 1) {
        #pragma unroll
        for (int bl = 0; bl < 4; ++bl) {
            Z[bl]  += __shfl_xor(Z[bl], d);
            U[bl]  += __shfl_xor(U[bl], d);
            Yv[bl] += __shfl_xor(Yv[bl], d);
        }
    }
    if (lane == 0) {
        #pragma unroll
        for (int bl = 0; bl < 4; ++bl) {
            pZ[(size_t)(bq + bl) * PSTRIDE + blockIdx.x] = Z[bl];
            pU[(size_t)(bq + bl) * PSTRIDE + blockIdx.x] = U[bl];
            pY[(size_t)(bq + bl) * PSTRIDE + blockIdx.x] = Yv[bl];
        }
    }
}

// K3: per-b combine partials -> loss_b = log(N+1) - U/(Y*Z)
__global__ __launch_bounds__(256) void k_reduce(const float* __restrict__ pZ,
                                                const float* __restrict__ pU,
                                                const float* __restrict__ pY,
                                                float* __restrict__ lb) {
    int b = blockIdx.x, tid = threadIdx.x;
    float z = 0.f, u = 0.f, yy = 0.f;
    for (int i = tid; i < NBLK; i += 256) {
        z  += pZ[(size_t)b * PSTRIDE + i];
        u  += pU[(size_t)b * PSTRIDE + i];
        yy += pY[(size_t)b * PSTRIDE + i];
    }
    #pragma unroll
    for (int d = 1; d < 64; d <<= 1) {
        z += __shfl_xor(z, d); u += __shfl_xor(u, d); yy += __shfl_xor(yy, d);
    }
    __shared__ float sz[4], su[4], sy[4];
    int w = tid >> 6;
    if ((tid & 63) == 0) { sz[w] = z; su[w] = u; sy[w] = yy; }
    __syncthreads();
    if (tid == 0) {
        float Zt = sz[0] + sz[1] + sz[2] + sz[3];
        float Ut = su[0] + su[1] + su[2] + su[3];
        float Yt = sy[0] + sy[1] + sy[2] + sy[3];
        lb[b] = logf((float)(NS + 1)) - Ut / (Yt * Zt);
    }
}

// K4: mean over b
__global__ __launch_bounds__(64) void k_final(const float* __restrict__ lb,
                                              float* __restrict__ out) {
    int lane = threadIdx.x;
    float v = (lane < BATCH) ? lb[lane] : 0.f;
    #pragma unroll
    for (int d = 1; d < 64; d <<= 1) v += __shfl_xor(v, d);
    if (lane == 0) out[0] = v * (1.0f / BATCH);
}

extern "C" void kernel_launch(void* const* d_in, const int* in_sizes, int n_in,
                              void* d_out, int out_size, void* d_ws, size_t ws_size,
                              hipStream_t stream) {
    const float* pred  = (const float*)d_in[0];
    const float* song  = (const float*)d_in[1];
    const float* x_inv = (const float*)d_in[2];
    const float* y     = (const float*)d_in[3];
    float* out = (float*)d_out;

    char* ws = (char*)d_ws;
    unsigned short* predp = (unsigned short*)ws;                   // 256 KiB (32 rows/b stride)
    float* pZ = (float*)(ws + 262144);                             // 32*800*4 = 100 KiB
    float* pU = (float*)(ws + 262144 + 102400);
    float* pY = (float*)(ws + 262144 + 2 * 102400);
    float* lb = (float*)(ws + 262144 + 3 * 102400);

    k_prednorm<<<dim3(SEQ, BATCH), 64, 0, stream>>>(pred, predp);
    k_main<<<NBLK, 512, 0, stream>>>(song, predp, x_inv, y, pZ, pU, pY);
    k_reduce<<<BATCH, 256, 0, stream>>>(pZ, pU, pY, lb);
    k_final<<<1, 64, 0, stream>>>(lb, out);
}

// Round 6
// 61.175 us; speedup vs baseline: 3.8487x; 1.0618x over previous
//
#include <hip/hip_runtime.h>

typedef __attribute__((ext_vector_type(8))) short short8;
typedef __attribute__((ext_vector_type(4))) float f32x4;
typedef __attribute__((ext_vector_type(4))) unsigned int u32x4;

#define NS    100000
#define DIM   128
#define BATCH 32
#define SEQ   20
#define NBLK  782              /* ceil(100000 / 128) */
#define NCH   25               /* stats chunks per batch row; 25000 f4 % 25 == 0 */

__device__ __forceinline__ unsigned int f2bf(float f) {
    unsigned int u = __float_as_uint(f);
    unsigned int r = u + 0x7FFFu + ((u >> 16) & 1u);
    return r >> 16;
}

// K1: normalize pred rows -> bf16 predp[b][32 rows][128]; rows 0..19 only.
__global__ __launch_bounds__(64) void k_prednorm(const float* __restrict__ pred,
                                                 unsigned short* __restrict__ predp) {
    int s = blockIdx.x, b = blockIdx.y;    // grid (20, 32)
    int lane = threadIdx.x;
    float2 v = ((const float2*)(pred + (size_t)(b * SEQ + s) * DIM))[lane];
    float ss = v.x * v.x + v.y * v.y;
    #pragma unroll
    for (int d = 1; d < 64; d <<= 1) ss += __shfl_xor(ss, d);
    float sc = 1.0f / fmaxf(sqrtf(ss), 1e-8f);
    unsigned int val = f2bf(v.x * sc) | (f2bf(v.y * sc) << 16);
    ((unsigned int*)(predp + ((size_t)b * 32 + s) * DIM))[lane] = val;
}

// K2: lean GEMM. 8 waves x 4 b's = 32 b per block; 128 songs/block.
// ONE barrier total; after it waves free-run from LDS and store sim.
__global__ __launch_bounds__(512) void k_gemm(const float* __restrict__ song,
                                              const unsigned short* __restrict__ predp,
                                              float* __restrict__ sim) {
    const int tid  = threadIdx.x;
    const int lane = tid & 63;
    const int wid  = tid >> 6;          // 0..7
    const int l16  = lane & 15;
    const int g    = lane >> 4;         // 0..3
    const int song0 = blockIdx.x * 128;
    const int bq    = wid * 4;

    // ---- issue song loads first (HBM, longest latency; 8 in flight) ----
    int gn = song0 + wid * 16 + l16;    // wave stages songs [song0+wid*16, +16)
    gn = gn < NS ? gn : NS - 1;
    const float* sp = song + (size_t)gn * DIM + g * 8;
    float4 v0[4], v1[4];
    #pragma unroll
    for (int kt = 0; kt < 4; ++kt) {
        v0[kt] = *(const float4*)(sp + kt * 32);
        v1[kt] = *(const float4*)(sp + kt * 32 + 4);
    }

    // ---- A fragments from predp (L2/L3-hot, 256 KB total) ----
    short8 Am[4][4];                    // [b_local][kt] rows 0..15
    short8 At[4];                       // packed tail: row l16 -> b=bq+(l16>>2), s=16+(l16&3)
    #pragma unroll
    for (int bl = 0; bl < 4; ++bl)
        #pragma unroll
        for (int kt = 0; kt < 4; ++kt)
            Am[bl][kt] = *(const short8*)(predp + ((size_t)(bq + bl) * 32 + l16) * DIM + kt * 32 + g * 8);
    {
        int tb = bq + (l16 >> 2), ts = 16 + (l16 & 3);
        #pragma unroll
        for (int kt = 0; kt < 4; ++kt)
            At[kt] = *(const short8*)(predp + ((size_t)tb * 32 + ts) * DIM + kt * 32 + g * 8);
    }

    // ---- normalize + pack bf16 + swizzled LDS stage ----
    __shared__ u32x4 lds_[2048];        // 32 KB: [row 0..127][16 slots x 16B]
    char* const lds = (char*)lds_;
    float ss = 0.f;
    #pragma unroll
    for (int kt = 0; kt < 4; ++kt) {
        ss += v0[kt].x*v0[kt].x + v0[kt].y*v0[kt].y + v0[kt].z*v0[kt].z + v0[kt].w*v0[kt].w;
        ss += v1[kt].x*v1[kt].x + v1[kt].y*v1[kt].y + v1[kt].z*v1[kt].z + v1[kt].w*v1[kt].w;
    }
    ss += __shfl_xor(ss, 16); ss += __shfl_xor(ss, 32);
    float sc = 1.0f / fmaxf(sqrtf(ss), 1e-8f);
    int row = wid * 16 + l16;           // row&7 == l16&7
    #pragma unroll
    for (int kt = 0; kt < 4; ++kt) {
        u32x4 o;
        o[0] = f2bf(v0[kt].x * sc) | (f2bf(v0[kt].y * sc) << 16);
        o[1] = f2bf(v0[kt].z * sc) | (f2bf(v0[kt].w * sc) << 16);
        o[2] = f2bf(v1[kt].x * sc) | (f2bf(v1[kt].y * sc) << 16);
        o[3] = f2bf(v1[kt].z * sc) | (f2bf(v1[kt].w * sc) << 16);
        *(u32x4*)(lds + row * 256 + (((kt * 4 + g) ^ (row & 7)) << 4)) = o;
    }
    __syncthreads();                    // the ONLY barrier

    // ---- free-running main loop: 4 chunks of 32 songs ----
    #pragma unroll 1
    for (int ch = 0; ch < 4; ++ch) {
        const char* r0 = lds + (ch * 32 + l16) * 256;        // tile0 rows; &7 == l16&7
        const char* r1 = r0 + 16 * 256;                      // tile1 rows; same &7
        short8 B0[4], B1[4];
        #pragma unroll
        for (int kt = 0; kt < 4; ++kt) {
            int po = (((kt * 4 + g) ^ (l16 & 7)) << 4);
            B0[kt] = *(const short8*)(r0 + po);
            B1[kt] = *(const short8*)(r1 + po);
        }
        f32x4 aM[4][2];
        f32x4 aT0 = {0,0,0,0}, aT1 = {0,0,0,0};
        #pragma unroll
        for (int bl = 0; bl < 4; ++bl) { aM[bl][0] = (f32x4){0,0,0,0}; aM[bl][1] = (f32x4){0,0,0,0}; }
        #pragma unroll
        for (int kt = 0; kt < 4; ++kt) {
            #pragma unroll
            for (int bl = 0; bl < 4; ++bl) {
                aM[bl][0] = __builtin_amdgcn_mfma_f32_16x16x32_bf16(Am[bl][kt], B0[kt], aM[bl][0], 0, 0, 0);
                aM[bl][1] = __builtin_amdgcn_mfma_f32_16x16x32_bf16(Am[bl][kt], B1[kt], aM[bl][1], 0, 0, 0);
            }
            aT0 = __builtin_amdgcn_mfma_f32_16x16x32_bf16(At[kt], B0[kt], aT0, 0, 0, 0);
            aT1 = __builtin_amdgcn_mfma_f32_16x16x32_bf16(At[kt], B1[kt], aT1, 0, 0, 0);
        }
        // ---- epilogue: per-b max over 20 rows -> masked coalesced store ----
        int n = song0 + ch * 32 + (lane & 31);
        bool do_st = (lane < 32) && (n < NS);
        float mt0 = fmaxf(fmaxf(aT0[0], aT0[1]), fmaxf(aT0[2], aT0[3]));
        float mt1 = fmaxf(fmaxf(aT1[0], aT1[1]), fmaxf(aT1[2], aT1[3]));
        #pragma unroll
        for (int bl = 0; bl < 4; ++bl) {
            float m0 = fmaxf(fmaxf(aM[bl][0][0], aM[bl][0][1]), fmaxf(aM[bl][0][2], aM[bl][0][3]));
            float m1 = fmaxf(fmaxf(aM[bl][1][0], aM[bl][1][1]), fmaxf(aM[bl][1][2], aM[bl][1][3]));
            m0 = (g == bl) ? fmaxf(m0, mt0) : m0;    // tail rows of b=bq+bl live in g==bl
            m1 = (g == bl) ? fmaxf(m1, mt1) : m1;
            m0 = fmaxf(m0, __shfl_xor(m0, 16)); m0 = fmaxf(m0, __shfl_xor(m0, 32));
            m1 = fmaxf(m1, __shfl_xor(m1, 16)); m1 = fmaxf(m1, __shfl_xor(m1, 32));
            float mo = (lane & 16) ? m1 : m0;        // lanes0-15: songs +l16; 16-31: +16+l16
            if (do_st) sim[(size_t)(bq + bl) * NS + n] = mo;
        }
    }
}

// K3: streaming pass: Z = sum e^{s*x}, Y = sum e^y, U = sum e^{s*x+y}
__global__ __launch_bounds__(256) void k_stats(const float* __restrict__ sim,
                                               const float* __restrict__ x_inv,
                                               const float* __restrict__ y,
                                               float* __restrict__ pZ,
                                               float* __restrict__ pY,
                                               float* __restrict__ pU) {
    int c = blockIdx.x, b = blockIdx.y;
    int tid = threadIdx.x;
    size_t base4 = (size_t)b * (NS / 4) + (size_t)c * 1000;
    const float4* s4 = (const float4*)sim + base4;
    const float4* x4 = (const float4*)x_inv + base4;
    const float4* y4 = (const float4*)y + base4;
    float z = 0.f, yy = 0.f, u = 0.f;
    for (int i = tid; i < 1000; i += 256) {
        float4 sv = s4[i], xv = x4[i], yv = y4[i];
        float e0 = __expf(sv.x * xv.x), e1 = __expf(sv.y * xv.y);
        float e2 = __expf(sv.z * xv.z), e3 = __expf(sv.w * xv.w);
        float f0 = __expf(yv.x), f1 = __expf(yv.y);
        float f2 = __expf(yv.z), f3 = __expf(yv.w);
        z  += (e0 + e1) + (e2 + e3);
        yy += (f0 + f1) + (f2 + f3);
        u  += (e0 * f0 + e1 * f1) + (e2 * f2 + e3 * f3);
    }
    #pragma unroll
    for (int d = 1; d < 64; d <<= 1) {
        z += __shfl_xor(z, d); yy += __shfl_xor(yy, d); u += __shfl_xor(u, d);
    }
    __shared__ float sz[4], sy[4], su[4];
    int w = tid >> 6;
    if ((tid & 63) == 0) { sz[w] = z; sy[w] = yy; su[w] = u; }
    __syncthreads();
    if (tid == 0) {
        int o = b * NCH + c;
        pZ[o] = sz[0] + sz[1] + sz[2] + sz[3];
        pY[o] = sy[0] + sy[1] + sy[2] + sy[3];
        pU[o] = su[0] + su[1] + su[2] + su[3];
    }
}

// K4: combine 800 partials -> per-b loss -> mean
__global__ __launch_bounds__(1024) void k_finish(const float* __restrict__ pZ,
                                                 const float* __restrict__ pY,
                                                 const float* __restrict__ pU,
                                                 float* __restrict__ out) {
    __shared__ float sZ[BATCH * NCH], sY[BATCH * NCH], sU[BATCH * NCH], lb[BATCH];
    int tid = threadIdx.x;
    if (tid < BATCH * NCH) { sZ[tid] = pZ[tid]; sY[tid] = pY[tid]; sU[tid] = pU[tid]; }
    __syncthreads();
    if (tid < BATCH) {
        float Z = 0.f, Y = 0.f, U = 0.f;
        #pragma unroll
        for (int j = 0; j < NCH; ++j) {
            Z += sZ[tid * NCH + j]; Y += sY[tid * NCH + j]; U += sU[tid * NCH + j];
        }
        lb[tid] = logf((float)(NS + 1)) - U / (Y * Z);
    }
    __syncthreads();
    if (tid < 64) {
        float v = (tid < BATCH) ? lb[tid] : 0.f;
        #pragma unroll
        for (int d = 1; d < 64; d <<= 1) v += __shfl_xor(v, d);
        if (tid == 0) out[0] = v * (1.0f / BATCH);
    }
}

extern "C" void kernel_launch(void* const* d_in, const int* in_sizes, int n_in,
                              void* d_out, int out_size, void* d_ws, size_t ws_size,
                              hipStream_t stream) {
    const float* pred  = (const float*)d_in[0];
    const float* song  = (const float*)d_in[1];
    const float* x_inv = (const float*)d_in[2];
    const float* y     = (const float*)d_in[3];
    float* out = (float*)d_out;

    char* ws = (char*)d_ws;
    unsigned short* predp = (unsigned short*)ws;                   // 256 KiB
    float* sim = (float*)(ws + 262144);                            // 12.8 MB
    float* pZ  = (float*)(ws + 262144 + 12800000);                 // 800 f
    float* pY  = pZ + BATCH * NCH;
    float* pU  = pY + BATCH * NCH;

    k_prednorm<<<dim3(SEQ, BATCH), 64, 0, stream>>>(pred, predp);
    k_gemm<<<NBLK, 512, 0, stream>>>(song, predp, sim);
    k_stats<<<dim3(NCH, BATCH), 256, 0, stream>>>(sim, x_inv, y, pZ, pY, pU);
    k_finish<<<1, 1024, 0, stream>>>(pZ, pY, pU, out);
}